// Round 4
// baseline (322.729 us; speedup 1.0000x reference)
//
#include <hip/hip_runtime.h>
#include <hip/hip_bf16.h>

// Problem constants (setup_inputs: B=2, N=256, D=256, H=8, LEN=516)
#define NPAIR 131072   // B*N*N
#define NUNIT 8192     // NPAIR / 16 pairs per MFMA tile
#define NH    8        // heads
#define NN    256      // N (k-dimension for topk / ind)
#define NROWS 512      // B*N rows for topk
#define LEN   516      // 2*D + 4
#define EPSV  1e-8f

typedef __attribute__((ext_vector_type(8))) short bf16x8;  // MFMA A/B frag
typedef __attribute__((ext_vector_type(4))) float f32x4;   // MFMA C/D frag

__device__ __forceinline__ unsigned int pk2(float x, float y) {
    union { __hip_bfloat162 h; unsigned int u; } c;
    c.h = __float22bfloat162_rn(make_float2(x, y));
    return c.u;   // low 16 = x, high 16 = y
}
__device__ __forceinline__ bf16x8 pack8(float4 a, float4 b) {
    union { unsigned int u[4]; bf16x8 v; } r;
    r.u[0] = pk2(a.x, a.y);
    r.u[1] = pk2(a.z, a.w);
    r.u[2] = pk2(b.x, b.y);
    r.u[3] = pk2(b.z, b.w);
    return r.v;
}

// Kernel 1: one 16x16x32 MFMA tile block per 16 consecutive pairs.
// A-frag and B-frag share the same lane->element map (lane l holds
// row/col m=l&15, k=(l>>4)*8+j), so Q-row frags and K-row frags are loaded
// ONCE and reused:  mfma(Qf,Kf)=Q@K^T (diag=q.k), mfma(Qf,Qf) diag=|q|^2,
// mfma(Kf,Kf) diag=|k|^2, mfma(Qf,Wq)+mfma(Kf,Wk)=head projections.
//
// v2: W fragments moved from 64 persistent registers (which spilled into
// AGPRs, reg-capping occupancy at ~42%) into 16 KB of LDS, prepacked
// bf16, one ds_read_b128 per frag per chunk (16 B/lane contiguous ->
// conflict-free). Grid 1024->2048 blocks: one unit per wave.
// v2.2: zero_ind as its own launch (round-0-proven path).
// v2.3: identical resubmit — rounds 1-3 all died to container-level
// failures across three DIFFERENT binaries (kernel-independent; round-0
// timing showed input push at 1505 s, near the session budget). Audit
// x3 found no OOB/misalignment/divergent-barrier/unbounded-loop.
// No __launch_bounds__ min-occupancy: r2/r3 showed occupancy-capped
// allocation provokes scratch spill (WRITE_SIZE 199-264 MB).
__global__ void fused_main(
    const float* __restrict__ Q, const float* __restrict__ K,
    const float* __restrict__ SQ, const float* __restrict__ SK,
    const float* __restrict__ ROI, const float* __restrict__ W,
    const float* __restrict__ Bb, float* __restrict__ out,
    float* __restrict__ scores)
{
    __shared__ bf16x8 wq_lds[8][64];   // [chunk][lane] prepacked W (q half)
    __shared__ bf16x8 wk_lds[8][64];   // [chunk][lane] prepacked W (k half)

    // Stage per-lane W fragments to LDS (512 entries per array; 2 per
    // thread). Entry (c, l): lane l's B-frag for chunk c.
    for (int e = threadIdx.x; e < 512; e += 256) {
        const int c     = e >> 6;
        const int ll    = e & 63;
        const int koff2 = (ll >> 4) * 8;
        const int hh2   = ll & 7;          // == (ll & 15) & 7
        const float* wp = W + hh2 * LEN + c * 32 + koff2;
        wq_lds[c][ll] = pack8(*(const float4*)wp,
                              *(const float4*)(wp + 4));
        wk_lds[c][ll] = pack8(*(const float4*)(wp + 256),
                              *(const float4*)(wp + 260));
    }
    __syncthreads();

    const int l    = threadIdx.x & 63;
    const int quad = l >> 4;        // 0..3
    const int m    = l & 15;        // tile row (pairs) / tile col (heads)
    const int hh   = m & 7;         // W row for this lane's output column
    const int koff = quad * 8;      // k-offset within a 32-wide chunk
    const int nwaves = (gridDim.x * blockDim.x) >> 6;
    const int wave = (blockIdx.x * blockDim.x + threadIdx.x) >> 6;

    // Spatial tail + bias for this lane's head column (hoisted).
    const float4 wt = *(const float4*)(W + hh * LEN + 512);
    const float bh = Bb[hh];

    const bool diag_owner = ((m >> 2) == quad);   // owns diag element m
    const int  dreg = m & 3;

    for (int u = wave; u < NUNIT; u += nwaves) {
        const int p0 = u * 16;
        const float* qbase = Q + (size_t)(p0 + m) * 256 + koff;
        const float* kbase = K + (size_t)(p0 + m) * 256 + koff;

        f32x4 a_qk = {0.f, 0.f, 0.f, 0.f};
        f32x4 a_qq = {0.f, 0.f, 0.f, 0.f};
        f32x4 a_kk = {0.f, 0.f, 0.f, 0.f};
        f32x4 a_pr = {0.f, 0.f, 0.f, 0.f};

#pragma unroll
        for (int c = 0; c < 8; ++c) {
            const float4 qa = *(const float4*)(qbase + c * 32);
            const float4 qb = *(const float4*)(qbase + c * 32 + 4);
            const float4 ka = *(const float4*)(kbase + c * 32);
            const float4 kb = *(const float4*)(kbase + c * 32 + 4);
            const bf16x8 qf = pack8(qa, qb);
            const bf16x8 kf = pack8(ka, kb);
            const bf16x8 wqf = wq_lds[c][l];   // ds_read_b128
            const bf16x8 wkf = wk_lds[c][l];   // ds_read_b128
            a_qk = __builtin_amdgcn_mfma_f32_16x16x32_bf16(qf, kf, a_qk, 0, 0, 0);
            a_qq = __builtin_amdgcn_mfma_f32_16x16x32_bf16(qf, qf, a_qq, 0, 0, 0);
            a_kk = __builtin_amdgcn_mfma_f32_16x16x32_bf16(kf, kf, a_kk, 0, 0, 0);
            a_pr = __builtin_amdgcn_mfma_f32_16x16x32_bf16(qf, wqf, a_pr, 0, 0, 0);
            a_pr = __builtin_amdgcn_mfma_f32_16x16x32_bf16(kf, wkf, a_pr, 0, 0, 0);
        }

        // Cosine scores: diag elements of qk/qq/kk tiles.
        if (diag_owner) {
            const float qk = a_qk[dreg];
            const float qq = a_qq[dreg];
            const float kk = a_kk[dreg];
            const float d = fmaxf(sqrtf(qq), EPSV) * fmaxf(sqrtf(kk), EPSV);
            scores[p0 + m] = fmaxf(qk / d, 0.0f);
        }

        // Projection epilogue: lane's column h = m (<8 valid); 4 rows.
        if (m < NH) {
#pragma unroll
            for (int r = 0; r < 4; ++r) {
                const int p = p0 + quad * 4 + r;
                const float2 sq = ((const float2*)SQ)[p];
                const float2 sk = ((const float2*)SK)[p];
                const float roi = ROI[p];
                const float x = a_pr[r] + sq.x * wt.x + sq.y * wt.y
                                        + sk.x * wt.z + sk.y * wt.w + bh;
                out[(size_t)p * NH + m] = roi / (1.0f + __expf(-x));
            }
        }
    }
}

// Kernel 2: zero the indicator (ws is poisoned 0xAA before each launch).
__global__ void zero_ind(float* __restrict__ ind) {
    ind[threadIdx.x] = 0.0f;
}

// Kernel 3: per (b,q) row, extract top-k indices (stable: ties -> lower
// index) and mark ind[idx] = 1.0. One wave per row.
__global__ __launch_bounds__(64) void topk_kernel(
    const float* __restrict__ scores, float* __restrict__ ind,
    const int* __restrict__ node_num)
{
    const int row = blockIdx.x;
    const int lane = threadIdx.x;
    const float4 v4 = *(const float4*)(scores + row * NN + lane * 4);
    float v[4] = {v4.x, v4.y, v4.z, v4.w};

    int Kk = node_num[0];
    if (Kk > NN) Kk = NN;
    for (int t = 0; t < Kk; t++) {
        float mv = v[0];
        int mi = lane * 4;
#pragma unroll
        for (int j = 1; j < 4; j++) {
            if (v[j] > mv) { mv = v[j]; mi = lane * 4 + j; }
        }
        for (int off = 32; off > 0; off >>= 1) {
            const float ov = __shfl_xor(mv, off, 64);
            const int   oi = __shfl_xor(mi, off, 64);
            if (ov > mv || (ov == mv && oi < mi)) { mv = ov; mi = oi; }
        }
        if (lane == 0) ind[mi] = 1.0f;             // idempotent 1.0 store
        if ((mi >> 2) == lane) v[mi & 3] = -1.0f;  // remove (scores >= 0)
    }
}

// Kernel 4: out *= ind[k]; float4 over out (element e: k = (e/8)%256).
__global__ __launch_bounds__(256) void apply_ind_kernel(
    float* __restrict__ out, const float* __restrict__ ind)
{
    const int i = blockIdx.x * blockDim.x + threadIdx.x;  // float4 index
    float4 v = ((float4*)out)[i];
    const float m = ind[(i >> 1) & (NN - 1)];
    v.x *= m; v.y *= m; v.z *= m; v.w *= m;
    ((float4*)out)[i] = v;
}

extern "C" void kernel_launch(void* const* d_in, const int* in_sizes, int n_in,
                              void* d_out, int out_size, void* d_ws, size_t ws_size,
                              hipStream_t stream)
{
    const float* Q   = (const float*)d_in[0];
    const float* K   = (const float*)d_in[1];
    const float* SQ  = (const float*)d_in[2];
    const float* SK  = (const float*)d_in[3];
    const float* ROI = (const float*)d_in[4];
    const float* W   = (const float*)d_in[5];
    const float* Bb  = (const float*)d_in[6];
    const int* node_num = (const int*)d_in[7];

    float* out = (float*)d_out;
    float* scores = (float*)d_ws;          // NPAIR floats (512 KB)
    float* ind = scores + NPAIR;           // NN floats

    fused_main<<<2048, 256, 0, stream>>>(Q, K, SQ, SK, ROI, W, Bb, out,
                                         scores);
    zero_ind<<<1, 256, 0, stream>>>(ind);
    topk_kernel<<<NROWS, 64, 0, stream>>>(scores, ind, node_num);
    apply_ind_kernel<<<out_size / 4 / 256, 256, 0, stream>>>(out, ind);
}